// Round 6
// baseline (146.694 us; speedup 1.0000x reference)
//
#include <hip/hip_runtime.h>

#define N_NODES 50000
#define N_EDGES 600000
#define D 128
#define SCAN_BLOCKS ((N_NODES + 255) / 256)   // 196

typedef __attribute__((ext_vector_type(8))) short short8v;
typedef __attribute__((ext_vector_type(4))) float f32x4;

__device__ __forceinline__ unsigned short f2bf(float v) {
    unsigned u = __builtin_bit_cast(unsigned, v);
    u += 0x7FFFu + ((u >> 16) & 1u);          // round-to-nearest-even
    return (unsigned short)(u >> 16);
}
__device__ __forceinline__ float bf2f(unsigned short h) {
    unsigned u = ((unsigned)h) << 16;
    return __builtin_bit_cast(float, u);
}

// ===================== prep: W hi/lo split + x -> bf16 ======================
// blocks [0,128): split W into Bh/Bl (B^T layout = original W layout)
// blocks [128, 128+3125): convert x (50000x128 f32) to bf16 rows
__global__ __launch_bounds__(256) void prep_kernel(
    const float* __restrict__ Wl, const float* __restrict__ Wr,
    unsigned short* __restrict__ Bh, unsigned short* __restrict__ Bl,
    const float* __restrict__ x, unsigned short* __restrict__ xbf)
{
    int bid = blockIdx.x;
    if (bid < 128) {
        int t = bid * 256 + threadIdx.x;          // covers 128*256 W elements
        int n = t >> 8;
        int k = t & 255;
        float w = (k < 128) ? Wl[n * 128 + k] : Wr[n * 128 + (k - 128)];
        unsigned short h = f2bf(w);
        Bh[t] = h;
        Bl[t] = f2bf(w - bf2f(h));
    } else {
        int t = (bid - 128) * 256 + threadIdx.x;  // 8 floats per thread
        if (t < N_NODES * D / 8) {
            const float4* p = (const float4*)(x + (size_t)t * 8);
            float4 a = p[0], b = p[1];
            short8v o;
            o[0] = (short)f2bf(a.x); o[1] = (short)f2bf(a.y);
            o[2] = (short)f2bf(a.z); o[3] = (short)f2bf(a.w);
            o[4] = (short)f2bf(b.x); o[5] = (short)f2bf(b.y);
            o[6] = (short)f2bf(b.z); o[7] = (short)f2bf(b.w);
            *(short8v*)(xbf + (size_t)t * 8) = o;
        }
    }
}

// ============================== CSR-build path ==============================

__global__ void zero_ints(int* __restrict__ p, int n) {
    int i = blockIdx.x * blockDim.x + threadIdx.x;
    if (i < n) p[i] = 0;
}

__global__ __launch_bounds__(256) void hist_kernel(
    const int* __restrict__ ei, int* __restrict__ counts)
{
    int e = blockIdx.x * blockDim.x + threadIdx.x;
    if (e >= N_EDGES) return;
    atomicAdd(&counts[ei[N_EDGES + e]], 1);
}

__global__ __launch_bounds__(256) void scan_phase1(
    const int* __restrict__ counts, int* __restrict__ blockSums)
{
    int i = blockIdx.x * 256 + threadIdx.x;
    int v = (i < N_NODES) ? counts[i] : 0;
#pragma unroll
    for (int off = 32; off > 0; off >>= 1) v += __shfl_down(v, off, 64);
    __shared__ int wsum[4];
    int lane = threadIdx.x & 63, wid = threadIdx.x >> 6;
    if (lane == 0) wsum[wid] = v;
    __syncthreads();
    if (threadIdx.x == 0)
        blockSums[blockIdx.x] = wsum[0] + wsum[1] + wsum[2] + wsum[3];
}

__global__ __launch_bounds__(256) void scan_phase2(
    const int* __restrict__ blockSums, int* __restrict__ blockOffs,
    int* __restrict__ offs)
{
    __shared__ int sh[256];
    int t = threadIdx.x;
    int v = (t < SCAN_BLOCKS) ? blockSums[t] : 0;
    sh[t] = v;
    __syncthreads();
    for (int off = 1; off < 256; off <<= 1) {
        int u = (t >= off) ? sh[t - off] : 0;
        __syncthreads();
        sh[t] += u;
        __syncthreads();
    }
    if (t < SCAN_BLOCKS) blockOffs[t] = sh[t] - v;   // exclusive
    if (t == 0) offs[N_NODES] = N_EDGES;
}

__global__ __launch_bounds__(256) void scan_phase3(
    const int* __restrict__ counts,
    const int* __restrict__ blockOffs,
    int* __restrict__ offs, int* __restrict__ woff)
{
    int t = threadIdx.x;
    int i = blockIdx.x * 256 + t;
    int v = (i < N_NODES) ? counts[i] : 0;
    int lane = t & 63, wid = t >> 6;
    int s = v;
#pragma unroll
    for (int off = 1; off < 64; off <<= 1) {
        int u = __shfl_up(s, off, 64);
        if (lane >= off) s += u;
    }
    __shared__ int wsum[4];
    if (lane == 63) wsum[wid] = s;
    __syncthreads();
    int wadd = 0;
    for (int w = 0; w < wid; w++) wadd += wsum[w];
    if (i < N_NODES) {
        int excl = blockOffs[blockIdx.x] + s + wadd - v;
        offs[i] = excl;
        woff[i] = excl;
    }
}

__global__ __launch_bounds__(256) void pack_kernel(
    const int* __restrict__ ei,
    const int* __restrict__ ew,
    int* __restrict__ woff,
    unsigned* __restrict__ packed)
{
    int e = blockIdx.x * blockDim.x + threadIdx.x;
    if (e >= N_EDGES) return;
    int dst = ei[N_EDGES + e];
    int pos = atomicAdd(&woff[dst], 1);
    packed[pos] = (unsigned)ei[e] | ((unsigned)ew[e] << 16);
}

// one 64-lane wave per node; bf16 x-gather (256 B/row), f32 accumulate.
// Edge loop unrolled x8: 8 packed loads, then 8 independent x-row loads in
// flight (MLP=8), then FMAs. prop row written exactly once.
__global__ __launch_bounds__(256) void aggregate_kernel(
    const unsigned short* __restrict__ xbf,
    const float* __restrict__ emb,
    const int* __restrict__ offs,
    const unsigned* __restrict__ packed,
    float* __restrict__ prop)   // aliases d_out
{
    int node = blockIdx.x * 4 + (threadIdx.x >> 6);
    if (node >= N_NODES) return;
    int c = (threadIdx.x & 63) * 2;

    int beg = offs[node], end = offs[node + 1];
    float2 acc = make_float2(0.f, 0.f);

    int i = beg;
    for (; i + 8 <= end; i += 8) {
        unsigned pk[8];
#pragma unroll
        for (int q = 0; q < 8; q++) pk[q] = packed[i + q];
        unsigned xr[8];
#pragma unroll
        for (int q = 0; q < 8; q++)
            xr[q] = *(const unsigned*)(xbf + (size_t)(pk[q] & 0xFFFFu) * D + c);
#pragma unroll
        for (int q = 0; q < 8; q++) {
            float2 ev = *(const float2*)(emb + (size_t)(pk[q] >> 16) * D + c);
            acc.x += ev.x * bf2f((unsigned short)(xr[q] & 0xFFFFu));
            acc.y += ev.y * bf2f((unsigned short)(xr[q] >> 16));
        }
    }
    for (; i < end; i++) {
        unsigned p = packed[i];
        unsigned xu = *(const unsigned*)(xbf + (size_t)(p & 0xFFFFu) * D + c);
        float2 ev = *(const float2*)(emb + (size_t)(p >> 16) * D + c);
        acc.x += ev.x * bf2f((unsigned short)(xu & 0xFFFFu));
        acc.y += ev.y * bf2f((unsigned short)(xu >> 16));
    }
    *(float2*)(prop + (size_t)node * D + c) = acc;
}

// ============================ fallback (atomic) =============================

__global__ void zero_kernel(float4* __restrict__ out, int n4) {
    int i = blockIdx.x * blockDim.x + threadIdx.x;
    int stride = gridDim.x * blockDim.x;
    for (; i < n4; i += stride) out[i] = make_float4(0.f, 0.f, 0.f, 0.f);
}

__global__ __launch_bounds__(256) void scatter_kernel(
    const float* __restrict__ x,
    const float* __restrict__ emb,
    const int*   __restrict__ ei,
    const int*   __restrict__ ew,
    float*       __restrict__ prop)
{
    int gid = blockIdx.x * blockDim.x + threadIdx.x;
    int e = gid >> 5;
    if (e >= N_EDGES) return;
    int d4 = (gid & 31) * 4;
    int src = ei[e];
    int dst = ei[N_EDGES + e];
    int w   = ew[e];
    float4 ev = *(const float4*)(emb + (size_t)w * D + d4);
    float4 xv = *(const float4*)(x + (size_t)src * D + d4);
    float* p = prop + (size_t)dst * D + d4;
    atomicAdd(p + 0, ev.x * xv.x);
    atomicAdd(p + 1, ev.y * xv.y);
    atomicAdd(p + 2, ev.z * xv.z);
    atomicAdd(p + 3, ev.w * xv.w);
}

// ======================= bf16x2-split MFMA GEMM =============================
// out = [x | prop] @ [Wl^T ; Wr^T] + (b_l + b_r),   K = 256, N = 128
// Split:  A ~= Ah + Al,  B ~= Bh + Bl  (bf16 each);
// out ~= Ah@Bh + Al@Bh + Ah@Bl   (lo*lo dropped, ~1e-5).

__global__ __launch_bounds__(256) void mfma_gemm(
    const float* __restrict__ x,
    float*       __restrict__ out,          // prop on entry, result on exit
    const unsigned short* __restrict__ Bh,  // [128][256]
    const unsigned short* __restrict__ Bl,
    const float* __restrict__ bl_,
    const float* __restrict__ br_)
{
    __shared__ unsigned short Ah_s[128 * 40];
    __shared__ unsigned short Al_s[128 * 40];
    __shared__ unsigned short Bh_s[128 * 40];
    __shared__ unsigned short Bl_s[128 * 40];

    const int tid  = threadIdx.x;
    const int lane = tid & 63;
    const int wave = tid >> 6;
    const int row0 = blockIdx.x * 128;

    const int wr0 = (wave >> 1) * 64;
    const int wc0 = (wave & 1) * 64;
    const int lr  = lane & 15;
    const int lk8 = (lane >> 4) * 8;

    const int srow  = tid >> 1;
    const int skoff = (tid & 1) * 16;

    f32x4 acc[4][4];
#pragma unroll
    for (int i = 0; i < 4; i++)
#pragma unroll
        for (int j = 0; j < 4; j++)
            acc[i][j] = (f32x4){0.f, 0.f, 0.f, 0.f};

    for (int kc = 0; kc < 8; ++kc) {
        const int kbase = kc * 32;
        {
            const float* Asrc = (kbase < 128) ? x : out;
            const int acol = (kbase & 127) + skoff;
            const int grow = row0 + srow;
            float v[16];
            if (grow < N_NODES) {
                const float4* p = (const float4*)(Asrc + (size_t)grow * D + acol);
#pragma unroll
                for (int q = 0; q < 4; q++) {
                    float4 f = p[q];
                    v[q*4+0] = f.x; v[q*4+1] = f.y; v[q*4+2] = f.z; v[q*4+3] = f.w;
                }
            } else {
#pragma unroll
                for (int q = 0; q < 16; q++) v[q] = 0.f;
            }
            short8v h0, h1, l0, l1;
#pragma unroll
            for (int q = 0; q < 8; q++) {
                unsigned short h = f2bf(v[q]);
                h0[q] = (short)h;
                l0[q] = (short)f2bf(v[q] - bf2f(h));
            }
#pragma unroll
            for (int q = 0; q < 8; q++) {
                unsigned short h = f2bf(v[q + 8]);
                h1[q] = (short)h;
                l1[q] = (short)f2bf(v[q + 8] - bf2f(h));
            }
            *(short8v*)(Ah_s + srow * 40 + skoff)     = h0;
            *(short8v*)(Ah_s + srow * 40 + skoff + 8) = h1;
            *(short8v*)(Al_s + srow * 40 + skoff)     = l0;
            *(short8v*)(Al_s + srow * 40 + skoff + 8) = l1;
        }
        {
            const size_t boff = (size_t)srow * 256 + kbase + skoff;
            short8v bh0 = *(const short8v*)(Bh + boff);
            short8v bh1 = *(const short8v*)(Bh + boff + 8);
            short8v bl0 = *(const short8v*)(Bl + boff);
            short8v bl1 = *(const short8v*)(Bl + boff + 8);
            *(short8v*)(Bh_s + srow * 40 + skoff)     = bh0;
            *(short8v*)(Bh_s + srow * 40 + skoff + 8) = bh1;
            *(short8v*)(Bl_s + srow * 40 + skoff)     = bl0;
            *(short8v*)(Bl_s + srow * 40 + skoff + 8) = bl1;
        }
        __syncthreads();
        short8v afh[4], afl[4];
#pragma unroll
        for (int rt = 0; rt < 4; rt++) {
            int ar = wr0 + rt * 16 + lr;
            afh[rt] = *(const short8v*)(Ah_s + ar * 40 + lk8);
            afl[rt] = *(const short8v*)(Al_s + ar * 40 + lk8);
        }
#pragma unroll
        for (int ct = 0; ct < 4; ct++) {
            int bc = wc0 + ct * 16 + lr;
            short8v bfh = *(const short8v*)(Bh_s + bc * 40 + lk8);
            short8v bfl = *(const short8v*)(Bl_s + bc * 40 + lk8);
#pragma unroll
            for (int rt = 0; rt < 4; rt++)
                acc[rt][ct] = __builtin_amdgcn_mfma_f32_16x16x32_bf16(afh[rt], bfh, acc[rt][ct], 0, 0, 0);
#pragma unroll
            for (int rt = 0; rt < 4; rt++)
                acc[rt][ct] = __builtin_amdgcn_mfma_f32_16x16x32_bf16(afl[rt], bfh, acc[rt][ct], 0, 0, 0);
#pragma unroll
            for (int rt = 0; rt < 4; rt++)
                acc[rt][ct] = __builtin_amdgcn_mfma_f32_16x16x32_bf16(afh[rt], bfl, acc[rt][ct], 0, 0, 0);
        }
        __syncthreads();
    }

    const int drow = (lane >> 4) * 4;
#pragma unroll
    for (int ct = 0; ct < 4; ct++) {
        int col = wc0 + ct * 16 + lr;
        float bias = bl_[col] + br_[col];
#pragma unroll
        for (int rt = 0; rt < 4; rt++) {
#pragma unroll
            for (int r = 0; r < 4; r++) {
                int grow = row0 + wr0 + rt * 16 + drow + r;
                if (grow < N_NODES)
                    out[(size_t)grow * D + col] = acc[rt][ct][r] + bias;
            }
        }
    }
}

// ============================================================================
extern "C" void kernel_launch(void* const* d_in, const int* in_sizes, int n_in,
                              void* d_out, int out_size, void* d_ws, size_t ws_size,
                              hipStream_t stream) {
    const float* x    = (const float*)d_in[0];
    const float* emb  = (const float*)d_in[1];
    const float* W_l  = (const float*)d_in[2];
    const float* b_l  = (const float*)d_in[3];
    const float* W_r  = (const float*)d_in[4];
    const float* b_r  = (const float*)d_in[5];
    const int*   ei   = (const int*)d_in[6];
    const int*   ew   = (const int*)d_in[7];

    float* out = (float*)d_out;

    char* wsp = (char*)d_ws;
    unsigned short* Bh  = (unsigned short*)wsp; wsp += 128 * 256 * sizeof(unsigned short);
    unsigned short* Bl  = (unsigned short*)wsp; wsp += 128 * 256 * sizeof(unsigned short);
    unsigned short* xbf = (unsigned short*)wsp; wsp += (size_t)N_NODES * D * sizeof(unsigned short);
    int*      counts    = (int*)wsp;     wsp += N_NODES * sizeof(int);
    int*      offs      = (int*)wsp;     wsp += (N_NODES + 1) * sizeof(int);
    int*      woff      = (int*)wsp;     wsp += N_NODES * sizeof(int);
    int*      blockSums = (int*)wsp;     wsp += SCAN_BLOCKS * sizeof(int);
    int*      blockOffs = (int*)wsp;     wsp += SCAN_BLOCKS * sizeof(int);
    unsigned* packed    = (unsigned*)wsp; wsp += N_EDGES * sizeof(unsigned);
    size_t needed = (size_t)(wsp - (char*)d_ws);

    const int XPREP_BLOCKS = (N_NODES * D / 8 + 255) / 256;   // 3125

    if (ws_size >= needed) {
        // prep: W hi/lo split + x->bf16
        prep_kernel<<<128 + XPREP_BLOCKS, 256, 0, stream>>>(W_l, W_r, Bh, Bl, x, xbf);
        // CSR build + gather aggregate (no float atomics)
        zero_ints<<<(N_NODES + 255) / 256, 256, 0, stream>>>(counts, N_NODES);
        hist_kernel<<<(N_EDGES + 255) / 256, 256, 0, stream>>>(ei, counts);
        scan_phase1<<<SCAN_BLOCKS, 256, 0, stream>>>(counts, blockSums);
        scan_phase2<<<1, 256, 0, stream>>>(blockSums, blockOffs, offs);
        scan_phase3<<<SCAN_BLOCKS, 256, 0, stream>>>(counts, blockOffs, offs, woff);
        pack_kernel<<<(N_EDGES + 255) / 256, 256, 0, stream>>>(ei, ew, woff, packed);
        aggregate_kernel<<<(N_NODES + 3) / 4, 256, 0, stream>>>(xbf, emb, offs, packed, out);
        mfma_gemm<<<(N_NODES + 127) / 128, 256, 0, stream>>>(x, out, Bh, Bl, b_l, b_r);
    } else {
        // fallback: atomic scatter into d_out (needs only Bh/Bl in ws)
        prep_kernel<<<128, 256, 0, stream>>>(W_l, W_r, Bh, Bl, x, xbf);
        int n4 = N_NODES * D / 4;
        zero_kernel<<<(n4 + 255) / 256, 256, 0, stream>>>((float4*)out, n4);
        long long work = (long long)N_EDGES * 32;
        scatter_kernel<<<(int)((work + 255) / 256), 256, 0, stream>>>(x, emb, ei, ew, out);
        mfma_gemm<<<(N_NODES + 127) / 128, 256, 0, stream>>>(x, out, Bh, Bl, b_l, b_r);
    }
}

// Round 7
// 116.364 us; speedup vs baseline: 1.2606x; 1.2606x over previous
//
#include <hip/hip_runtime.h>

#define N_NODES 50000
#define N_EDGES 600000
#define D 128
#define SCAN_BLOCKS ((N_NODES + 255) / 256)   // 196

typedef __attribute__((ext_vector_type(8))) short short8v;
typedef __attribute__((ext_vector_type(4))) float f32x4;

__device__ __forceinline__ unsigned short f2bf(float v) {
    unsigned u = __builtin_bit_cast(unsigned, v);
    u += 0x7FFFu + ((u >> 16) & 1u);          // round-to-nearest-even
    return (unsigned short)(u >> 16);
}
__device__ __forceinline__ float bf2f(unsigned short h) {
    unsigned u = ((unsigned)h) << 16;
    return __builtin_bit_cast(float, u);
}

// ============ prep: W hi/lo split + x -> bf16 + zero counts =================
// blocks [0,128): split W into Bh/Bl (B^T layout = original W layout)
// blocks [128, 128+3125): convert x (50000x128 f32) to bf16 rows
// blocks [128+3125, 128+3125+196): zero counts
#define XPREP_BLOCKS ((N_NODES * D / 8 + 255) / 256)   // 3125
__global__ __launch_bounds__(256) void prep_kernel(
    const float* __restrict__ Wl, const float* __restrict__ Wr,
    unsigned short* __restrict__ Bh, unsigned short* __restrict__ Bl,
    const float* __restrict__ x, unsigned short* __restrict__ xbf,
    int* __restrict__ counts)
{
    int bid = blockIdx.x;
    if (bid < 128) {
        int t = bid * 256 + threadIdx.x;          // covers 128*256 W elements
        int n = t >> 8;
        int k = t & 255;
        float w = (k < 128) ? Wl[n * 128 + k] : Wr[n * 128 + (k - 128)];
        unsigned short h = f2bf(w);
        Bh[t] = h;
        Bl[t] = f2bf(w - bf2f(h));
    } else if (bid < 128 + XPREP_BLOCKS) {
        int t = (bid - 128) * 256 + threadIdx.x;  // 8 floats per thread
        if (t < N_NODES * D / 8) {
            const float4* p = (const float4*)(x + (size_t)t * 8);
            float4 a = p[0], b = p[1];
            short8v o;
            o[0] = (short)f2bf(a.x); o[1] = (short)f2bf(a.y);
            o[2] = (short)f2bf(a.z); o[3] = (short)f2bf(a.w);
            o[4] = (short)f2bf(b.x); o[5] = (short)f2bf(b.y);
            o[6] = (short)f2bf(b.z); o[7] = (short)f2bf(b.w);
            *(short8v*)(xbf + (size_t)t * 8) = o;
        }
    } else {
        int t = (bid - 128 - XPREP_BLOCKS) * 256 + threadIdx.x;
        if (t < N_NODES) counts[t] = 0;
    }
}

// ============================== CSR-build path ==============================

// histogram + per-edge rank (rank store is coalesced; atomic result consumed
// here, NOT in pack -> pack has no RMW in its dependency chain)
__global__ __launch_bounds__(256) void histrank_kernel(
    const int* __restrict__ ei, int* __restrict__ counts,
    int* __restrict__ rank)
{
    int e = blockIdx.x * blockDim.x + threadIdx.x;
    if (e >= N_EDGES) return;
    rank[e] = atomicAdd(&counts[ei[N_EDGES + e]], 1);
}

__global__ __launch_bounds__(256) void scan_phase1(
    const int* __restrict__ counts, int* __restrict__ blockSums)
{
    int i = blockIdx.x * 256 + threadIdx.x;
    int v = (i < N_NODES) ? counts[i] : 0;
#pragma unroll
    for (int off = 32; off > 0; off >>= 1) v += __shfl_down(v, off, 64);
    __shared__ int wsum[4];
    int lane = threadIdx.x & 63, wid = threadIdx.x >> 6;
    if (lane == 0) wsum[wid] = v;
    __syncthreads();
    if (threadIdx.x == 0)
        blockSums[blockIdx.x] = wsum[0] + wsum[1] + wsum[2] + wsum[3];
}

__global__ __launch_bounds__(256) void scan_phase2(
    const int* __restrict__ blockSums, int* __restrict__ blockOffs,
    int* __restrict__ offs)
{
    __shared__ int sh[256];
    int t = threadIdx.x;
    int v = (t < SCAN_BLOCKS) ? blockSums[t] : 0;
    sh[t] = v;
    __syncthreads();
    for (int off = 1; off < 256; off <<= 1) {
        int u = (t >= off) ? sh[t - off] : 0;
        __syncthreads();
        sh[t] += u;
        __syncthreads();
    }
    if (t < SCAN_BLOCKS) blockOffs[t] = sh[t] - v;   // exclusive
    if (t == 0) offs[N_NODES] = N_EDGES;
}

__global__ __launch_bounds__(256) void scan_phase3(
    const int* __restrict__ counts,
    const int* __restrict__ blockOffs,
    int* __restrict__ offs)
{
    int t = threadIdx.x;
    int i = blockIdx.x * 256 + t;
    int v = (i < N_NODES) ? counts[i] : 0;
    int lane = t & 63, wid = t >> 6;
    int s = v;
#pragma unroll
    for (int off = 1; off < 64; off <<= 1) {
        int u = __shfl_up(s, off, 64);
        if (lane >= off) s += u;
    }
    __shared__ int wsum[4];
    if (lane == 63) wsum[wid] = s;
    __syncthreads();
    int wadd = 0;
    for (int w = 0; w < wid; w++) wadd += wsum[w];
    if (i < N_NODES)
        offs[i] = blockOffs[blockIdx.x] + s + wadd - v;
}

// pos = offs[dst] + rank[e]; no atomic in the chain
__global__ __launch_bounds__(256) void pack_kernel(
    const int* __restrict__ ei,
    const int* __restrict__ ew,
    const int* __restrict__ offs,
    const int* __restrict__ rank,
    unsigned* __restrict__ packed)
{
    int e = blockIdx.x * blockDim.x + threadIdx.x;
    if (e >= N_EDGES) return;
    int dst = ei[N_EDGES + e];
    int r   = rank[e];
    int pos = offs[dst] + r;
    packed[pos] = (unsigned)ei[e] | ((unsigned)ew[e] << 16);
}

// one 64-lane wave per node; bf16 x-gather (256 B/row), f32 accumulate.
// Edge loop unrolled x8 -> 8 outstanding row loads per wave.
__global__ __launch_bounds__(256) void aggregate_kernel(
    const unsigned short* __restrict__ xbf,
    const float* __restrict__ emb,
    const int* __restrict__ offs,
    const unsigned* __restrict__ packed,
    float* __restrict__ prop)   // aliases d_out
{
    int node = blockIdx.x * 4 + (threadIdx.x >> 6);
    if (node >= N_NODES) return;
    int c = (threadIdx.x & 63) * 2;

    int beg = offs[node], end = offs[node + 1];
    float2 acc = make_float2(0.f, 0.f);

    int i = beg;
    for (; i + 8 <= end; i += 8) {
        unsigned pk[8];
#pragma unroll
        for (int q = 0; q < 8; q++) pk[q] = packed[i + q];
        unsigned xr[8];
#pragma unroll
        for (int q = 0; q < 8; q++)
            xr[q] = *(const unsigned*)(xbf + (size_t)(pk[q] & 0xFFFFu) * D + c);
#pragma unroll
        for (int q = 0; q < 8; q++) {
            float2 ev = *(const float2*)(emb + (size_t)(pk[q] >> 16) * D + c);
            acc.x += ev.x * bf2f((unsigned short)(xr[q] & 0xFFFFu));
            acc.y += ev.y * bf2f((unsigned short)(xr[q] >> 16));
        }
    }
    for (; i < end; i++) {
        unsigned p = packed[i];
        unsigned xu = *(const unsigned*)(xbf + (size_t)(p & 0xFFFFu) * D + c);
        float2 ev = *(const float2*)(emb + (size_t)(p >> 16) * D + c);
        acc.x += ev.x * bf2f((unsigned short)(xu & 0xFFFFu));
        acc.y += ev.y * bf2f((unsigned short)(xu >> 16));
    }
    *(float2*)(prop + (size_t)node * D + c) = acc;
}

// ============================ fallback (atomic) =============================

__global__ void zero_kernel(float4* __restrict__ out, int n4) {
    int i = blockIdx.x * blockDim.x + threadIdx.x;
    int stride = gridDim.x * blockDim.x;
    for (; i < n4; i += stride) out[i] = make_float4(0.f, 0.f, 0.f, 0.f);
}

__global__ __launch_bounds__(256) void scatter_kernel(
    const float* __restrict__ x,
    const float* __restrict__ emb,
    const int*   __restrict__ ei,
    const int*   __restrict__ ew,
    float*       __restrict__ prop)
{
    int gid = blockIdx.x * blockDim.x + threadIdx.x;
    int e = gid >> 5;
    if (e >= N_EDGES) return;
    int d4 = (gid & 31) * 4;
    int src = ei[e];
    int dst = ei[N_EDGES + e];
    int w   = ew[e];
    float4 ev = *(const float4*)(emb + (size_t)w * D + d4);
    float4 xv = *(const float4*)(x + (size_t)src * D + d4);
    float* p = prop + (size_t)dst * D + d4;
    atomicAdd(p + 0, ev.x * xv.x);
    atomicAdd(p + 1, ev.y * xv.y);
    atomicAdd(p + 2, ev.z * xv.z);
    atomicAdd(p + 3, ev.w * xv.w);
}

// ======================= bf16x2-split MFMA GEMM =============================
// out = [x | prop] @ [Wl^T ; Wr^T] + (b_l + b_r),   K = 256, N = 128
// Split:  A ~= Ah + Al,  B ~= Bh + Bl  (bf16 each);
// out ~= Ah@Bh + Al@Bh + Ah@Bl   (lo*lo dropped, ~1e-5).

__global__ __launch_bounds__(256) void mfma_gemm(
    const float* __restrict__ x,
    float*       __restrict__ out,          // prop on entry, result on exit
    const unsigned short* __restrict__ Bh,  // [128][256]
    const unsigned short* __restrict__ Bl,
    const float* __restrict__ bl_,
    const float* __restrict__ br_)
{
    __shared__ unsigned short Ah_s[128 * 40];
    __shared__ unsigned short Al_s[128 * 40];
    __shared__ unsigned short Bh_s[128 * 40];
    __shared__ unsigned short Bl_s[128 * 40];

    const int tid  = threadIdx.x;
    const int lane = tid & 63;
    const int wave = tid >> 6;
    const int row0 = blockIdx.x * 128;

    const int wr0 = (wave >> 1) * 64;
    const int wc0 = (wave & 1) * 64;
    const int lr  = lane & 15;
    const int lk8 = (lane >> 4) * 8;

    const int srow  = tid >> 1;
    const int skoff = (tid & 1) * 16;

    f32x4 acc[4][4];
#pragma unroll
    for (int i = 0; i < 4; i++)
#pragma unroll
        for (int j = 0; j < 4; j++)
            acc[i][j] = (f32x4){0.f, 0.f, 0.f, 0.f};

    for (int kc = 0; kc < 8; ++kc) {
        const int kbase = kc * 32;
        {
            const float* Asrc = (kbase < 128) ? x : out;
            const int acol = (kbase & 127) + skoff;
            const int grow = row0 + srow;
            float v[16];
            if (grow < N_NODES) {
                const float4* p = (const float4*)(Asrc + (size_t)grow * D + acol);
#pragma unroll
                for (int q = 0; q < 4; q++) {
                    float4 f = p[q];
                    v[q*4+0] = f.x; v[q*4+1] = f.y; v[q*4+2] = f.z; v[q*4+3] = f.w;
                }
            } else {
#pragma unroll
                for (int q = 0; q < 16; q++) v[q] = 0.f;
            }
            short8v h0, h1, l0, l1;
#pragma unroll
            for (int q = 0; q < 8; q++) {
                unsigned short h = f2bf(v[q]);
                h0[q] = (short)h;
                l0[q] = (short)f2bf(v[q] - bf2f(h));
            }
#pragma unroll
            for (int q = 0; q < 8; q++) {
                unsigned short h = f2bf(v[q + 8]);
                h1[q] = (short)h;
                l1[q] = (short)f2bf(v[q + 8] - bf2f(h));
            }
            *(short8v*)(Ah_s + srow * 40 + skoff)     = h0;
            *(short8v*)(Ah_s + srow * 40 + skoff + 8) = h1;
            *(short8v*)(Al_s + srow * 40 + skoff)     = l0;
            *(short8v*)(Al_s + srow * 40 + skoff + 8) = l1;
        }
        {
            const size_t boff = (size_t)srow * 256 + kbase + skoff;
            short8v bh0 = *(const short8v*)(Bh + boff);
            short8v bh1 = *(const short8v*)(Bh + boff + 8);
            short8v bl0 = *(const short8v*)(Bl + boff);
            short8v bl1 = *(const short8v*)(Bl + boff + 8);
            *(short8v*)(Bh_s + srow * 40 + skoff)     = bh0;
            *(short8v*)(Bh_s + srow * 40 + skoff + 8) = bh1;
            *(short8v*)(Bl_s + srow * 40 + skoff)     = bl0;
            *(short8v*)(Bl_s + srow * 40 + skoff + 8) = bl1;
        }
        __syncthreads();
        short8v afh[4], afl[4];
#pragma unroll
        for (int rt = 0; rt < 4; rt++) {
            int ar = wr0 + rt * 16 + lr;
            afh[rt] = *(const short8v*)(Ah_s + ar * 40 + lk8);
            afl[rt] = *(const short8v*)(Al_s + ar * 40 + lk8);
        }
#pragma unroll
        for (int ct = 0; ct < 4; ct++) {
            int bc = wc0 + ct * 16 + lr;
            short8v bfh = *(const short8v*)(Bh_s + bc * 40 + lk8);
            short8v bfl = *(const short8v*)(Bl_s + bc * 40 + lk8);
#pragma unroll
            for (int rt = 0; rt < 4; rt++)
                acc[rt][ct] = __builtin_amdgcn_mfma_f32_16x16x32_bf16(afh[rt], bfh, acc[rt][ct], 0, 0, 0);
#pragma unroll
            for (int rt = 0; rt < 4; rt++)
                acc[rt][ct] = __builtin_amdgcn_mfma_f32_16x16x32_bf16(afl[rt], bfh, acc[rt][ct], 0, 0, 0);
#pragma unroll
            for (int rt = 0; rt < 4; rt++)
                acc[rt][ct] = __builtin_amdgcn_mfma_f32_16x16x32_bf16(afh[rt], bfl, acc[rt][ct], 0, 0, 0);
        }
        __syncthreads();
    }

    const int drow = (lane >> 4) * 4;
#pragma unroll
    for (int ct = 0; ct < 4; ct++) {
        int col = wc0 + ct * 16 + lr;
        float bias = bl_[col] + br_[col];
#pragma unroll
        for (int rt = 0; rt < 4; rt++) {
#pragma unroll
            for (int r = 0; r < 4; r++) {
                int grow = row0 + wr0 + rt * 16 + drow + r;
                if (grow < N_NODES)
                    out[(size_t)grow * D + col] = acc[rt][ct][r] + bias;
            }
        }
    }
}

// ============================================================================
extern "C" void kernel_launch(void* const* d_in, const int* in_sizes, int n_in,
                              void* d_out, int out_size, void* d_ws, size_t ws_size,
                              hipStream_t stream) {
    const float* x    = (const float*)d_in[0];
    const float* emb  = (const float*)d_in[1];
    const float* W_l  = (const float*)d_in[2];
    const float* b_l  = (const float*)d_in[3];
    const float* W_r  = (const float*)d_in[4];
    const float* b_r  = (const float*)d_in[5];
    const int*   ei   = (const int*)d_in[6];
    const int*   ew   = (const int*)d_in[7];

    float* out = (float*)d_out;

    char* wsp = (char*)d_ws;
    unsigned short* Bh  = (unsigned short*)wsp; wsp += 128 * 256 * sizeof(unsigned short);
    unsigned short* Bl  = (unsigned short*)wsp; wsp += 128 * 256 * sizeof(unsigned short);
    unsigned short* xbf = (unsigned short*)wsp; wsp += (size_t)N_NODES * D * sizeof(unsigned short);
    int*      counts    = (int*)wsp;     wsp += N_NODES * sizeof(int);
    int*      offs      = (int*)wsp;     wsp += (N_NODES + 1) * sizeof(int);
    int*      rank      = (int*)wsp;     wsp += N_EDGES * sizeof(int);
    int*      blockSums = (int*)wsp;     wsp += SCAN_BLOCKS * sizeof(int);
    int*      blockOffs = (int*)wsp;     wsp += SCAN_BLOCKS * sizeof(int);
    unsigned* packed    = (unsigned*)wsp; wsp += N_EDGES * sizeof(unsigned);
    size_t needed = (size_t)(wsp - (char*)d_ws);

    if (ws_size >= needed) {
        // prep: W hi/lo split + x->bf16 + zero counts
        prep_kernel<<<128 + XPREP_BLOCKS + SCAN_BLOCKS, 256, 0, stream>>>(
            W_l, W_r, Bh, Bl, x, xbf, counts);
        // CSR build (rank-decoupled counting sort) + gather aggregate
        histrank_kernel<<<(N_EDGES + 255) / 256, 256, 0, stream>>>(ei, counts, rank);
        scan_phase1<<<SCAN_BLOCKS, 256, 0, stream>>>(counts, blockSums);
        scan_phase2<<<1, 256, 0, stream>>>(blockSums, blockOffs, offs);
        scan_phase3<<<SCAN_BLOCKS, 256, 0, stream>>>(counts, blockOffs, offs);
        pack_kernel<<<(N_EDGES + 255) / 256, 256, 0, stream>>>(ei, ew, offs, rank, packed);
        aggregate_kernel<<<(N_NODES + 3) / 4, 256, 0, stream>>>(xbf, emb, offs, packed, out);
        mfma_gemm<<<(N_NODES + 127) / 128, 256, 0, stream>>>(x, out, Bh, Bl, b_l, b_r);
    } else {
        // fallback: atomic scatter into d_out (needs only Bh/Bl in ws)
        prep_kernel<<<128, 256, 0, stream>>>(W_l, W_r, Bh, Bl, x, xbf, counts);
        int n4 = N_NODES * D / 4;
        zero_kernel<<<(n4 + 255) / 256, 256, 0, stream>>>((float4*)out, n4);
        long long work = (long long)N_EDGES * 32;
        scatter_kernel<<<(int)((work + 255) / 256), 256, 0, stream>>>(x, emb, ei, ew, out);
        mfma_gemm<<<(N_NODES + 127) / 128, 256, 0, stream>>>(x, out, Bh, Bl, b_l, b_r);
    }
}

// Round 8
// 115.108 us; speedup vs baseline: 1.2744x; 1.0109x over previous
//
#include <hip/hip_runtime.h>

#define N_NODES 50000
#define N_EDGES 600000
#define D 128
#define SCAN_BLOCKS ((N_NODES + 255) / 256)   // 196

typedef __attribute__((ext_vector_type(8))) short short8v;
typedef __attribute__((ext_vector_type(4))) float f32x4;

__device__ __forceinline__ unsigned short f2bf(float v) {
    unsigned u = __builtin_bit_cast(unsigned, v);
    u += 0x7FFFu + ((u >> 16) & 1u);          // round-to-nearest-even
    return (unsigned short)(u >> 16);
}
__device__ __forceinline__ float bf2f(unsigned short h) {
    unsigned u = ((unsigned)h) << 16;
    return __builtin_bit_cast(float, u);
}

// ============ prep: W hi/lo split + x -> bf16 + zero counts =================
#define XPREP_BLOCKS ((N_NODES * D / 8 + 255) / 256)   // 3125
__global__ __launch_bounds__(256) void prep_kernel(
    const float* __restrict__ Wl, const float* __restrict__ Wr,
    unsigned short* __restrict__ Bh, unsigned short* __restrict__ Bl,
    const float* __restrict__ x, unsigned short* __restrict__ xbf,
    int* __restrict__ counts)
{
    int bid = blockIdx.x;
    if (bid < 128) {
        int t = bid * 256 + threadIdx.x;          // covers 128*256 W elements
        int n = t >> 8;
        int k = t & 255;
        float w = (k < 128) ? Wl[n * 128 + k] : Wr[n * 128 + (k - 128)];
        unsigned short h = f2bf(w);
        Bh[t] = h;
        Bl[t] = f2bf(w - bf2f(h));
    } else if (bid < 128 + XPREP_BLOCKS) {
        int t = (bid - 128) * 256 + threadIdx.x;  // 8 floats per thread
        if (t < N_NODES * D / 8) {
            const float4* p = (const float4*)(x + (size_t)t * 8);
            float4 a = p[0], b = p[1];
            short8v o;
            o[0] = (short)f2bf(a.x); o[1] = (short)f2bf(a.y);
            o[2] = (short)f2bf(a.z); o[3] = (short)f2bf(a.w);
            o[4] = (short)f2bf(b.x); o[5] = (short)f2bf(b.y);
            o[6] = (short)f2bf(b.z); o[7] = (short)f2bf(b.w);
            *(short8v*)(xbf + (size_t)t * 8) = o;
        }
    } else {
        int t = (bid - 128 - XPREP_BLOCKS) * 256 + threadIdx.x;
        if (t < N_NODES) counts[t] = 0;
    }
}

// ============================== CSR-build path ==============================

// histogram + per-edge rank (atomic result stored coalesced; pack is RMW-free)
__global__ __launch_bounds__(256) void histrank_kernel(
    const int* __restrict__ ei, int* __restrict__ counts,
    int* __restrict__ rank)
{
    int e = blockIdx.x * blockDim.x + threadIdx.x;
    if (e >= N_EDGES) return;
    rank[e] = atomicAdd(&counts[ei[N_EDGES + e]], 1);
}

__global__ __launch_bounds__(256) void scan_phase1(
    const int* __restrict__ counts, int* __restrict__ blockSums)
{
    int i = blockIdx.x * 256 + threadIdx.x;
    int v = (i < N_NODES) ? counts[i] : 0;
#pragma unroll
    for (int off = 32; off > 0; off >>= 1) v += __shfl_down(v, off, 64);
    __shared__ int wsum[4];
    int lane = threadIdx.x & 63, wid = threadIdx.x >> 6;
    if (lane == 0) wsum[wid] = v;
    __syncthreads();
    if (threadIdx.x == 0)
        blockSums[blockIdx.x] = wsum[0] + wsum[1] + wsum[2] + wsum[3];
}

__global__ __launch_bounds__(256) void scan_phase2(
    const int* __restrict__ blockSums, int* __restrict__ blockOffs,
    int* __restrict__ offs)
{
    __shared__ int sh[256];
    int t = threadIdx.x;
    int v = (t < SCAN_BLOCKS) ? blockSums[t] : 0;
    sh[t] = v;
    __syncthreads();
    for (int off = 1; off < 256; off <<= 1) {
        int u = (t >= off) ? sh[t - off] : 0;
        __syncthreads();
        sh[t] += u;
        __syncthreads();
    }
    if (t < SCAN_BLOCKS) blockOffs[t] = sh[t] - v;   // exclusive
    if (t == 0) offs[N_NODES] = N_EDGES;
}

__global__ __launch_bounds__(256) void scan_phase3(
    const int* __restrict__ counts,
    const int* __restrict__ blockOffs,
    int* __restrict__ offs)
{
    int t = threadIdx.x;
    int i = blockIdx.x * 256 + t;
    int v = (i < N_NODES) ? counts[i] : 0;
    int lane = t & 63, wid = t >> 6;
    int s = v;
#pragma unroll
    for (int off = 1; off < 64; off <<= 1) {
        int u = __shfl_up(s, off, 64);
        if (lane >= off) s += u;
    }
    __shared__ int wsum[4];
    if (lane == 63) wsum[wid] = s;
    __syncthreads();
    int wadd = 0;
    for (int w = 0; w < wid; w++) wadd += wsum[w];
    if (i < N_NODES)
        offs[i] = blockOffs[blockIdx.x] + s + wadd - v;
}

// pos = offs[dst] + rank[e]; no atomic in the chain
__global__ __launch_bounds__(256) void pack_kernel(
    const int* __restrict__ ei,
    const int* __restrict__ ew,
    const int* __restrict__ offs,
    const int* __restrict__ rank,
    unsigned* __restrict__ packed)
{
    int e = blockIdx.x * blockDim.x + threadIdx.x;
    if (e >= N_EDGES) return;
    int dst = ei[N_EDGES + e];
    int r   = rank[e];
    int pos = offs[dst] + r;
    packed[pos] = (unsigned)ei[e] | ((unsigned)ew[e] << 16);
}

// one 64-lane wave per node; bf16 x-gather (256 B/row), f32 accumulate.
// Clamped full-MLP batches of 16: ALWAYS 16 independent row loads in flight,
// masked accumulate — no serial remainder loop. emb staged in LDS (lgkm pipe).
__global__ __launch_bounds__(256) void aggregate_kernel(
    const unsigned short* __restrict__ xbf,
    const float* __restrict__ emb,
    const int* __restrict__ offs,
    const unsigned* __restrict__ packed,
    float* __restrict__ prop)   // aliases d_out
{
    __shared__ float emb_s[10][D];
    for (int i = threadIdx.x; i < 10 * D; i += 256)
        emb_s[i >> 7][i & 127] = emb[i];
    __syncthreads();

    int node = blockIdx.x * 4 + (threadIdx.x >> 6);
    if (node >= N_NODES) return;
    int c = (threadIdx.x & 63) * 2;

    int beg = offs[node], end = offs[node + 1];
    float2 acc = make_float2(0.f, 0.f);

    for (int i = beg; i < end; i += 16) {
        unsigned pk[16];
#pragma unroll
        for (int q = 0; q < 16; q++) {
            int j = i + q;
            j = (j < end) ? j : end - 1;      // end>beg guaranteed inside loop
            pk[q] = packed[j];
        }
        unsigned xr[16];
#pragma unroll
        for (int q = 0; q < 16; q++)
            xr[q] = *(const unsigned*)(xbf + (size_t)(pk[q] & 0xFFFFu) * D + c);
#pragma unroll
        for (int q = 0; q < 16; q++) {
            float s = (i + q < end) ? 1.f : 0.f;
            const float* er = &emb_s[pk[q] >> 16][c];
            acc.x += s * er[0] * bf2f((unsigned short)(xr[q] & 0xFFFFu));
            acc.y += s * er[1] * bf2f((unsigned short)(xr[q] >> 16));
        }
    }
    *(float2*)(prop + (size_t)node * D + c) = acc;
}

// ============================ fallback (atomic) =============================

__global__ void zero_kernel(float4* __restrict__ out, int n4) {
    int i = blockIdx.x * blockDim.x + threadIdx.x;
    int stride = gridDim.x * blockDim.x;
    for (; i < n4; i += stride) out[i] = make_float4(0.f, 0.f, 0.f, 0.f);
}

__global__ __launch_bounds__(256) void scatter_kernel(
    const float* __restrict__ x,
    const float* __restrict__ emb,
    const int*   __restrict__ ei,
    const int*   __restrict__ ew,
    float*       __restrict__ prop)
{
    int gid = blockIdx.x * blockDim.x + threadIdx.x;
    int e = gid >> 5;
    if (e >= N_EDGES) return;
    int d4 = (gid & 31) * 4;
    int src = ei[e];
    int dst = ei[N_EDGES + e];
    int w   = ew[e];
    float4 ev = *(const float4*)(emb + (size_t)w * D + d4);
    float4 xv = *(const float4*)(x + (size_t)src * D + d4);
    float* p = prop + (size_t)dst * D + d4;
    atomicAdd(p + 0, ev.x * xv.x);
    atomicAdd(p + 1, ev.y * xv.y);
    atomicAdd(p + 2, ev.z * xv.z);
    atomicAdd(p + 3, ev.w * xv.w);
}

// ======================= bf16x2-split MFMA GEMM =============================
// out = [x | prop] @ [Wl^T ; Wr^T] + (b_l + b_r),   K = 256, N = 128

__global__ __launch_bounds__(256) void mfma_gemm(
    const float* __restrict__ x,
    float*       __restrict__ out,          // prop on entry, result on exit
    const unsigned short* __restrict__ Bh,  // [128][256]
    const unsigned short* __restrict__ Bl,
    const float* __restrict__ bl_,
    const float* __restrict__ br_)
{
    __shared__ unsigned short Ah_s[128 * 40];
    __shared__ unsigned short Al_s[128 * 40];
    __shared__ unsigned short Bh_s[128 * 40];
    __shared__ unsigned short Bl_s[128 * 40];

    const int tid  = threadIdx.x;
    const int lane = tid & 63;
    const int wave = tid >> 6;
    const int row0 = blockIdx.x * 128;

    const int wr0 = (wave >> 1) * 64;
    const int wc0 = (wave & 1) * 64;
    const int lr  = lane & 15;
    const int lk8 = (lane >> 4) * 8;

    const int srow  = tid >> 1;
    const int skoff = (tid & 1) * 16;

    f32x4 acc[4][4];
#pragma unroll
    for (int i = 0; i < 4; i++)
#pragma unroll
        for (int j = 0; j < 4; j++)
            acc[i][j] = (f32x4){0.f, 0.f, 0.f, 0.f};

    for (int kc = 0; kc < 8; ++kc) {
        const int kbase = kc * 32;
        {
            const float* Asrc = (kbase < 128) ? x : out;
            const int acol = (kbase & 127) + skoff;
            const int grow = row0 + srow;
            float v[16];
            if (grow < N_NODES) {
                const float4* p = (const float4*)(Asrc + (size_t)grow * D + acol);
#pragma unroll
                for (int q = 0; q < 4; q++) {
                    float4 f = p[q];
                    v[q*4+0] = f.x; v[q*4+1] = f.y; v[q*4+2] = f.z; v[q*4+3] = f.w;
                }
            } else {
#pragma unroll
                for (int q = 0; q < 16; q++) v[q] = 0.f;
            }
            short8v h0, h1, l0, l1;
#pragma unroll
            for (int q = 0; q < 8; q++) {
                unsigned short h = f2bf(v[q]);
                h0[q] = (short)h;
                l0[q] = (short)f2bf(v[q] - bf2f(h));
            }
#pragma unroll
            for (int q = 0; q < 8; q++) {
                unsigned short h = f2bf(v[q + 8]);
                h1[q] = (short)h;
                l1[q] = (short)f2bf(v[q + 8] - bf2f(h));
            }
            *(short8v*)(Ah_s + srow * 40 + skoff)     = h0;
            *(short8v*)(Ah_s + srow * 40 + skoff + 8) = h1;
            *(short8v*)(Al_s + srow * 40 + skoff)     = l0;
            *(short8v*)(Al_s + srow * 40 + skoff + 8) = l1;
        }
        {
            const size_t boff = (size_t)srow * 256 + kbase + skoff;
            short8v bh0 = *(const short8v*)(Bh + boff);
            short8v bh1 = *(const short8v*)(Bh + boff + 8);
            short8v bl0 = *(const short8v*)(Bl + boff);
            short8v bl1 = *(const short8v*)(Bl + boff + 8);
            *(short8v*)(Bh_s + srow * 40 + skoff)     = bh0;
            *(short8v*)(Bh_s + srow * 40 + skoff + 8) = bh1;
            *(short8v*)(Bl_s + srow * 40 + skoff)     = bl0;
            *(short8v*)(Bl_s + srow * 40 + skoff + 8) = bl1;
        }
        __syncthreads();
        short8v afh[4], afl[4];
#pragma unroll
        for (int rt = 0; rt < 4; rt++) {
            int ar = wr0 + rt * 16 + lr;
            afh[rt] = *(const short8v*)(Ah_s + ar * 40 + lk8);
            afl[rt] = *(const short8v*)(Al_s + ar * 40 + lk8);
        }
#pragma unroll
        for (int ct = 0; ct < 4; ct++) {
            int bc = wc0 + ct * 16 + lr;
            short8v bfh = *(const short8v*)(Bh_s + bc * 40 + lk8);
            short8v bfl = *(const short8v*)(Bl_s + bc * 40 + lk8);
#pragma unroll
            for (int rt = 0; rt < 4; rt++)
                acc[rt][ct] = __builtin_amdgcn_mfma_f32_16x16x32_bf16(afh[rt], bfh, acc[rt][ct], 0, 0, 0);
#pragma unroll
            for (int rt = 0; rt < 4; rt++)
                acc[rt][ct] = __builtin_amdgcn_mfma_f32_16x16x32_bf16(afl[rt], bfh, acc[rt][ct], 0, 0, 0);
#pragma unroll
            for (int rt = 0; rt < 4; rt++)
                acc[rt][ct] = __builtin_amdgcn_mfma_f32_16x16x32_bf16(afh[rt], bfl, acc[rt][ct], 0, 0, 0);
        }
        __syncthreads();
    }

    const int drow = (lane >> 4) * 4;
#pragma unroll
    for (int ct = 0; ct < 4; ct++) {
        int col = wc0 + ct * 16 + lr;
        float bias = bl_[col] + br_[col];
#pragma unroll
        for (int rt = 0; rt < 4; rt++) {
#pragma unroll
            for (int r = 0; r < 4; r++) {
                int grow = row0 + wr0 + rt * 16 + drow + r;
                if (grow < N_NODES)
                    out[(size_t)grow * D + col] = acc[rt][ct][r] + bias;
            }
        }
    }
}

// ============================================================================
extern "C" void kernel_launch(void* const* d_in, const int* in_sizes, int n_in,
                              void* d_out, int out_size, void* d_ws, size_t ws_size,
                              hipStream_t stream) {
    const float* x    = (const float*)d_in[0];
    const float* emb  = (const float*)d_in[1];
    const float* W_l  = (const float*)d_in[2];
    const float* b_l  = (const float*)d_in[3];
    const float* W_r  = (const float*)d_in[4];
    const float* b_r  = (const float*)d_in[5];
    const int*   ei   = (const int*)d_in[6];
    const int*   ew   = (const int*)d_in[7];

    float* out = (float*)d_out;

    char* wsp = (char*)d_ws;
    unsigned short* Bh  = (unsigned short*)wsp; wsp += 128 * 256 * sizeof(unsigned short);
    unsigned short* Bl  = (unsigned short*)wsp; wsp += 128 * 256 * sizeof(unsigned short);
    unsigned short* xbf = (unsigned short*)wsp; wsp += (size_t)N_NODES * D * sizeof(unsigned short);
    int*      counts    = (int*)wsp;     wsp += N_NODES * sizeof(int);
    int*      offs      = (int*)wsp;     wsp += (N_NODES + 1) * sizeof(int);
    int*      rank      = (int*)wsp;     wsp += N_EDGES * sizeof(int);
    int*      blockSums = (int*)wsp;     wsp += SCAN_BLOCKS * sizeof(int);
    int*      blockOffs = (int*)wsp;     wsp += SCAN_BLOCKS * sizeof(int);
    unsigned* packed    = (unsigned*)wsp; wsp += N_EDGES * sizeof(unsigned);
    size_t needed = (size_t)(wsp - (char*)d_ws);

    if (ws_size >= needed) {
        prep_kernel<<<128 + XPREP_BLOCKS + SCAN_BLOCKS, 256, 0, stream>>>(
            W_l, W_r, Bh, Bl, x, xbf, counts);
        histrank_kernel<<<(N_EDGES + 255) / 256, 256, 0, stream>>>(ei, counts, rank);
        scan_phase1<<<SCAN_BLOCKS, 256, 0, stream>>>(counts, blockSums);
        scan_phase2<<<1, 256, 0, stream>>>(blockSums, blockOffs, offs);
        scan_phase3<<<SCAN_BLOCKS, 256, 0, stream>>>(counts, blockOffs, offs);
        pack_kernel<<<(N_EDGES + 255) / 256, 256, 0, stream>>>(ei, ew, offs, rank, packed);
        aggregate_kernel<<<(N_NODES + 3) / 4, 256, 0, stream>>>(xbf, emb, offs, packed, out);
        mfma_gemm<<<(N_NODES + 127) / 128, 256, 0, stream>>>(x, out, Bh, Bl, b_l, b_r);
    } else {
        prep_kernel<<<128, 256, 0, stream>>>(W_l, W_r, Bh, Bl, x, xbf, counts);
        int n4 = N_NODES * D / 4;
        zero_kernel<<<(n4 + 255) / 256, 256, 0, stream>>>((float4*)out, n4);
        long long work = (long long)N_EDGES * 32;
        scatter_kernel<<<(int)((work + 255) / 256), 256, 0, stream>>>(x, emb, ei, ew, out);
        mfma_gemm<<<(N_NODES + 127) / 128, 256, 0, stream>>>(x, out, Bh, Bl, b_l, b_r);
    }
}

// Round 9
// 106.685 us; speedup vs baseline: 1.3750x; 1.0790x over previous
//
#include <hip/hip_runtime.h>

#define N_NODES 50000
#define N_EDGES 600000
#define D 128
#define SCAN_BLOCKS ((N_NODES + 255) / 256)   // 196
#define PACK_CAP 1351680                      // >= 600000 + 15*50000 + 16, = 1320*1024
#define PFILL_BLOCKS (PACK_CAP / 1024)        // 1320
#define SENTINEL 50000u                       // src = zero row, w = 0

typedef __attribute__((ext_vector_type(8))) short short8v;
typedef __attribute__((ext_vector_type(4))) float f32x4;

__device__ __forceinline__ unsigned short f2bf(float v) {
    unsigned u = __builtin_bit_cast(unsigned, v);
    u += 0x7FFFu + ((u >> 16) & 1u);          // round-to-nearest-even
    return (unsigned short)(u >> 16);
}
__device__ __forceinline__ float bf2f(unsigned short h) {
    unsigned u = ((unsigned)h) << 16;
    return __builtin_bit_cast(float, u);
}

// ==== prep: W hi/lo split + x->bf16 + zero counts + sentinel prefill ========
#define XPREP_BLOCKS ((N_NODES * D / 8 + 255) / 256)   // 3125
__global__ __launch_bounds__(256) void prep_kernel(
    const float* __restrict__ Wl, const float* __restrict__ Wr,
    unsigned short* __restrict__ Bh, unsigned short* __restrict__ Bl,
    const float* __restrict__ x, unsigned short* __restrict__ xbf,
    int* __restrict__ counts, unsigned* __restrict__ packed)
{
    int bid = blockIdx.x;
    if (bid < 128) {
        int t = bid * 256 + threadIdx.x;          // covers 128*256 W elements
        int n = t >> 8;
        int k = t & 255;
        float w = (k < 128) ? Wl[n * 128 + k] : Wr[n * 128 + (k - 128)];
        unsigned short h = f2bf(w);
        Bh[t] = h;
        Bl[t] = f2bf(w - bf2f(h));
    } else if (bid < 128 + XPREP_BLOCKS) {
        int t = (bid - 128) * 256 + threadIdx.x;  // 8 floats per thread
        if (t < N_NODES * D / 8) {
            const float4* p = (const float4*)(x + (size_t)t * 8);
            float4 a = p[0], b = p[1];
            short8v o;
            o[0] = (short)f2bf(a.x); o[1] = (short)f2bf(a.y);
            o[2] = (short)f2bf(a.z); o[3] = (short)f2bf(a.w);
            o[4] = (short)f2bf(b.x); o[5] = (short)f2bf(b.y);
            o[6] = (short)f2bf(b.z); o[7] = (short)f2bf(b.w);
            *(short8v*)(xbf + (size_t)t * 8) = o;
        }
    } else if (bid < 128 + XPREP_BLOCKS + SCAN_BLOCKS) {
        int t = (bid - 128 - XPREP_BLOCKS) * 256 + threadIdx.x;
        if (t < N_NODES) counts[t] = 0;
    } else if (bid < 128 + XPREP_BLOCKS + SCAN_BLOCKS + PFILL_BLOCKS) {
        int t = (bid - 128 - XPREP_BLOCKS - SCAN_BLOCKS) * 1024 + threadIdx.x * 4;
        uint4 s = make_uint4(SENTINEL, SENTINEL, SENTINEL, SENTINEL);
        *(uint4*)(packed + t) = s;
    } else {
        // zero row of xbf at index N_NODES (gather target for sentinels)
        if (threadIdx.x < 16) {
            short8v z = (short8v){0,0,0,0,0,0,0,0};
            *(short8v*)(xbf + (size_t)N_NODES * D + threadIdx.x * 8) = z;
        }
    }
}

// ============================== CSR-build path ==============================

// histogram + per-edge rank (atomic result stored coalesced; pack is RMW-free)
__global__ __launch_bounds__(256) void histrank_kernel(
    const int* __restrict__ ei, int* __restrict__ counts,
    int* __restrict__ rank)
{
    int e = blockIdx.x * blockDim.x + threadIdx.x;
    if (e >= N_EDGES) return;
    rank[e] = atomicAdd(&counts[ei[N_EDGES + e]], 1);
}

// scans operate on PADDED counts: cp = (c+15) & ~15  (segments x16 for agg)
__global__ __launch_bounds__(256) void scan_phase1(
    const int* __restrict__ counts, int* __restrict__ blockSums)
{
    int i = blockIdx.x * 256 + threadIdx.x;
    int v = (i < N_NODES) ? ((counts[i] + 15) & ~15) : 0;
#pragma unroll
    for (int off = 32; off > 0; off >>= 1) v += __shfl_down(v, off, 64);
    __shared__ int wsum[4];
    int lane = threadIdx.x & 63, wid = threadIdx.x >> 6;
    if (lane == 0) wsum[wid] = v;
    __syncthreads();
    if (threadIdx.x == 0)
        blockSums[blockIdx.x] = wsum[0] + wsum[1] + wsum[2] + wsum[3];
}

__global__ __launch_bounds__(256) void scan_phase2(
    const int* __restrict__ blockSums, int* __restrict__ blockOffs,
    int* __restrict__ offs)
{
    __shared__ int sh[256];
    int t = threadIdx.x;
    int v = (t < SCAN_BLOCKS) ? blockSums[t] : 0;
    sh[t] = v;
    __syncthreads();
    for (int off = 1; off < 256; off <<= 1) {
        int u = (t >= off) ? sh[t - off] : 0;
        __syncthreads();
        sh[t] += u;
        __syncthreads();
    }
    if (t < SCAN_BLOCKS) blockOffs[t] = sh[t] - v;   // exclusive
    if (t == 255) offs[N_NODES] = sh[255];           // total PADDED length
}

__global__ __launch_bounds__(256) void scan_phase3(
    const int* __restrict__ counts,
    const int* __restrict__ blockOffs,
    int* __restrict__ offs)
{
    int t = threadIdx.x;
    int i = blockIdx.x * 256 + t;
    int v = (i < N_NODES) ? ((counts[i] + 15) & ~15) : 0;
    int lane = t & 63, wid = t >> 6;
    int s = v;
#pragma unroll
    for (int off = 1; off < 64; off <<= 1) {
        int u = __shfl_up(s, off, 64);
        if (lane >= off) s += u;
    }
    __shared__ int wsum[4];
    if (lane == 63) wsum[wid] = s;
    __syncthreads();
    int wadd = 0;
    for (int w = 0; w < wid; w++) wadd += wsum[w];
    if (i < N_NODES)
        offs[i] = blockOffs[blockIdx.x] + s + wadd - v;
}

// pos = offs[dst] + rank[e]; no atomic in the chain; sentinel slots untouched
__global__ __launch_bounds__(256) void pack_kernel(
    const int* __restrict__ ei,
    const int* __restrict__ ew,
    const int* __restrict__ offs,
    const int* __restrict__ rank,
    unsigned* __restrict__ packed)
{
    int e = blockIdx.x * blockDim.x + threadIdx.x;
    if (e >= N_EDGES) return;
    int dst = ei[N_EDGES + e];
    int r   = rank[e];
    int pos = offs[dst] + r;
    packed[pos] = (unsigned)ei[e] | ((unsigned)ew[e] << 16);
}

// 2 nodes per wave (half-wave each, 4 cols/lane, 8B bf16 gathers).
// Segments padded to x16 with sentinels -> inner loop has NO per-edge masks;
// exhausted half-waves redirect to a sentinel block (reads zero row).
__global__ __launch_bounds__(256) void aggregate_kernel(
    const unsigned short* __restrict__ xbf,
    const float* __restrict__ emb,
    const int* __restrict__ offs,
    const unsigned* __restrict__ packed,
    float* __restrict__ prop)   // aliases d_out
{
    __shared__ float emb_s[10][D];
    for (int i = threadIdx.x; i < 10 * D; i += 256)
        emb_s[i >> 7][i & 127] = emb[i];
    __syncthreads();

    int node = blockIdx.x * 8 + (threadIdx.x >> 5);
    if (node >= N_NODES) return;
    int c = (threadIdx.x & 31) * 4;

    int beg = offs[node], end = offs[node + 1];
    float4 acc = make_float4(0.f, 0.f, 0.f, 0.f);

    for (int i = beg; __any(i < end); i += 16) {
        int ib = (i < end) ? i : (PACK_CAP - 16);   // one cndmask per batch
        uint4 pk4[4];
#pragma unroll
        for (int qq = 0; qq < 4; qq++)
            pk4[qq] = *(const uint4*)(packed + ib + qq * 4);
        unsigned pk[16];
#pragma unroll
        for (int qq = 0; qq < 4; qq++) {
            pk[qq*4+0] = pk4[qq].x; pk[qq*4+1] = pk4[qq].y;
            pk[qq*4+2] = pk4[qq].z; pk[qq*4+3] = pk4[qq].w;
        }
        uint2 xr[16];
#pragma unroll
        for (int q = 0; q < 16; q++)
            xr[q] = *(const uint2*)(xbf + (size_t)(pk[q] & 0xFFFFu) * D + c);
#pragma unroll
        for (int q = 0; q < 16; q++) {
            float4 er = *(const float4*)&emb_s[pk[q] >> 16][c];
            acc.x += er.x * bf2f((unsigned short)(xr[q].x & 0xFFFFu));
            acc.y += er.y * bf2f((unsigned short)(xr[q].x >> 16));
            acc.z += er.z * bf2f((unsigned short)(xr[q].y & 0xFFFFu));
            acc.w += er.w * bf2f((unsigned short)(xr[q].y >> 16));
        }
    }
    *(float4*)(prop + (size_t)node * D + c) = acc;
}

// ============================ fallback (atomic) =============================

__global__ void zero_kernel(float4* __restrict__ out, int n4) {
    int i = blockIdx.x * blockDim.x + threadIdx.x;
    int stride = gridDim.x * blockDim.x;
    for (; i < n4; i += stride) out[i] = make_float4(0.f, 0.f, 0.f, 0.f);
}

__global__ __launch_bounds__(256) void scatter_kernel(
    const float* __restrict__ x,
    const float* __restrict__ emb,
    const int*   __restrict__ ei,
    const int*   __restrict__ ew,
    float*       __restrict__ prop)
{
    int gid = blockIdx.x * blockDim.x + threadIdx.x;
    int e = gid >> 5;
    if (e >= N_EDGES) return;
    int d4 = (gid & 31) * 4;
    int src = ei[e];
    int dst = ei[N_EDGES + e];
    int w   = ew[e];
    float4 ev = *(const float4*)(emb + (size_t)w * D + d4);
    float4 xv = *(const float4*)(x + (size_t)src * D + d4);
    float* p = prop + (size_t)dst * D + d4;
    atomicAdd(p + 0, ev.x * xv.x);
    atomicAdd(p + 1, ev.y * xv.y);
    atomicAdd(p + 2, ev.z * xv.z);
    atomicAdd(p + 3, ev.w * xv.w);
}

// ======================= bf16x2-split MFMA GEMM =============================
// out = [x | prop] @ [Wl^T ; Wr^T] + (b_l + b_r),   K = 256, N = 128

__global__ __launch_bounds__(256) void mfma_gemm(
    const float* __restrict__ x,
    float*       __restrict__ out,          // prop on entry, result on exit
    const unsigned short* __restrict__ Bh,  // [128][256]
    const unsigned short* __restrict__ Bl,
    const float* __restrict__ bl_,
    const float* __restrict__ br_)
{
    __shared__ unsigned short Ah_s[128 * 40];
    __shared__ unsigned short Al_s[128 * 40];
    __shared__ unsigned short Bh_s[128 * 40];
    __shared__ unsigned short Bl_s[128 * 40];

    const int tid  = threadIdx.x;
    const int lane = tid & 63;
    const int wave = tid >> 6;
    const int row0 = blockIdx.x * 128;

    const int wr0 = (wave >> 1) * 64;
    const int wc0 = (wave & 1) * 64;
    const int lr  = lane & 15;
    const int lk8 = (lane >> 4) * 8;

    const int srow  = tid >> 1;
    const int skoff = (tid & 1) * 16;

    f32x4 acc[4][4];
#pragma unroll
    for (int i = 0; i < 4; i++)
#pragma unroll
        for (int j = 0; j < 4; j++)
            acc[i][j] = (f32x4){0.f, 0.f, 0.f, 0.f};

    for (int kc = 0; kc < 8; ++kc) {
        const int kbase = kc * 32;
        {
            const float* Asrc = (kbase < 128) ? x : out;
            const int acol = (kbase & 127) + skoff;
            const int grow = row0 + srow;
            float v[16];
            if (grow < N_NODES) {
                const float4* p = (const float4*)(Asrc + (size_t)grow * D + acol);
#pragma unroll
                for (int q = 0; q < 4; q++) {
                    float4 f = p[q];
                    v[q*4+0] = f.x; v[q*4+1] = f.y; v[q*4+2] = f.z; v[q*4+3] = f.w;
                }
            } else {
#pragma unroll
                for (int q = 0; q < 16; q++) v[q] = 0.f;
            }
            short8v h0, h1, l0, l1;
#pragma unroll
            for (int q = 0; q < 8; q++) {
                unsigned short h = f2bf(v[q]);
                h0[q] = (short)h;
                l0[q] = (short)f2bf(v[q] - bf2f(h));
            }
#pragma unroll
            for (int q = 0; q < 8; q++) {
                unsigned short h = f2bf(v[q + 8]);
                h1[q] = (short)h;
                l1[q] = (short)f2bf(v[q + 8] - bf2f(h));
            }
            *(short8v*)(Ah_s + srow * 40 + skoff)     = h0;
            *(short8v*)(Ah_s + srow * 40 + skoff + 8) = h1;
            *(short8v*)(Al_s + srow * 40 + skoff)     = l0;
            *(short8v*)(Al_s + srow * 40 + skoff + 8) = l1;
        }
        {
            const size_t boff = (size_t)srow * 256 + kbase + skoff;
            short8v bh0 = *(const short8v*)(Bh + boff);
            short8v bh1 = *(const short8v*)(Bh + boff + 8);
            short8v bl0 = *(const short8v*)(Bl + boff);
            short8v bl1 = *(const short8v*)(Bl + boff + 8);
            *(short8v*)(Bh_s + srow * 40 + skoff)     = bh0;
            *(short8v*)(Bh_s + srow * 40 + skoff + 8) = bh1;
            *(short8v*)(Bl_s + srow * 40 + skoff)     = bl0;
            *(short8v*)(Bl_s + srow * 40 + skoff + 8) = bl1;
        }
        __syncthreads();
        short8v afh[4], afl[4];
#pragma unroll
        for (int rt = 0; rt < 4; rt++) {
            int ar = wr0 + rt * 16 + lr;
            afh[rt] = *(const short8v*)(Ah_s + ar * 40 + lk8);
            afl[rt] = *(const short8v*)(Al_s + ar * 40 + lk8);
        }
#pragma unroll
        for (int ct = 0; ct < 4; ct++) {
            int bc = wc0 + ct * 16 + lr;
            short8v bfh = *(const short8v*)(Bh_s + bc * 40 + lk8);
            short8v bfl = *(const short8v*)(Bl_s + bc * 40 + lk8);
#pragma unroll
            for (int rt = 0; rt < 4; rt++)
                acc[rt][ct] = __builtin_amdgcn_mfma_f32_16x16x32_bf16(afh[rt], bfh, acc[rt][ct], 0, 0, 0);
#pragma unroll
            for (int rt = 0; rt < 4; rt++)
                acc[rt][ct] = __builtin_amdgcn_mfma_f32_16x16x32_bf16(afl[rt], bfh, acc[rt][ct], 0, 0, 0);
#pragma unroll
            for (int rt = 0; rt < 4; rt++)
                acc[rt][ct] = __builtin_amdgcn_mfma_f32_16x16x32_bf16(afh[rt], bfl, acc[rt][ct], 0, 0, 0);
        }
        __syncthreads();
    }

    const int drow = (lane >> 4) * 4;
#pragma unroll
    for (int ct = 0; ct < 4; ct++) {
        int col = wc0 + ct * 16 + lr;
        float bias = bl_[col] + br_[col];
#pragma unroll
        for (int rt = 0; rt < 4; rt++) {
#pragma unroll
            for (int r = 0; r < 4; r++) {
                int grow = row0 + wr0 + rt * 16 + drow + r;
                if (grow < N_NODES)
                    out[(size_t)grow * D + col] = acc[rt][ct][r] + bias;
            }
        }
    }
}

// ============================================================================
extern "C" void kernel_launch(void* const* d_in, const int* in_sizes, int n_in,
                              void* d_out, int out_size, void* d_ws, size_t ws_size,
                              hipStream_t stream) {
    const float* x    = (const float*)d_in[0];
    const float* emb  = (const float*)d_in[1];
    const float* W_l  = (const float*)d_in[2];
    const float* b_l  = (const float*)d_in[3];
    const float* W_r  = (const float*)d_in[4];
    const float* b_r  = (const float*)d_in[5];
    const int*   ei   = (const int*)d_in[6];
    const int*   ew   = (const int*)d_in[7];

    float* out = (float*)d_out;

    char* wsp = (char*)d_ws;
    unsigned short* Bh  = (unsigned short*)wsp; wsp += 128 * 256 * sizeof(unsigned short);
    unsigned short* Bl  = (unsigned short*)wsp; wsp += 128 * 256 * sizeof(unsigned short);
    unsigned short* xbf = (unsigned short*)wsp; wsp += (size_t)(N_NODES + 1) * D * sizeof(unsigned short);
    int*      counts    = (int*)wsp;     wsp += N_NODES * sizeof(int);
    int*      offs      = (int*)wsp;     wsp += (N_NODES + 1) * sizeof(int);
    int*      rank      = (int*)wsp;     wsp += N_EDGES * sizeof(int);
    int*      blockSums = (int*)wsp;     wsp += SCAN_BLOCKS * sizeof(int);
    int*      blockOffs = (int*)wsp;     wsp += SCAN_BLOCKS * sizeof(int);
    unsigned* packed    = (unsigned*)wsp; wsp += (size_t)PACK_CAP * sizeof(unsigned);
    size_t needed = (size_t)(wsp - (char*)d_ws);

    if (ws_size >= needed) {
        prep_kernel<<<128 + XPREP_BLOCKS + SCAN_BLOCKS + PFILL_BLOCKS + 1, 256, 0, stream>>>(
            W_l, W_r, Bh, Bl, x, xbf, counts, packed);
        histrank_kernel<<<(N_EDGES + 255) / 256, 256, 0, stream>>>(ei, counts, rank);
        scan_phase1<<<SCAN_BLOCKS, 256, 0, stream>>>(counts, blockSums);
        scan_phase2<<<1, 256, 0, stream>>>(blockSums, blockOffs, offs);
        scan_phase3<<<SCAN_BLOCKS, 256, 0, stream>>>(counts, blockOffs, offs);
        pack_kernel<<<(N_EDGES + 255) / 256, 256, 0, stream>>>(ei, ew, offs, rank, packed);
        aggregate_kernel<<<(N_NODES + 7) / 8, 256, 0, stream>>>(xbf, emb, offs, packed, out);
        mfma_gemm<<<(N_NODES + 127) / 128, 256, 0, stream>>>(x, out, Bh, Bl, b_l, b_r);
    } else {
        prep_kernel<<<128, 256, 0, stream>>>(W_l, W_r, Bh, Bl, x, xbf, counts, packed);
        int n4 = N_NODES * D / 4;
        zero_kernel<<<(n4 + 255) / 256, 256, 0, stream>>>((float4*)out, n4);
        long long work = (long long)N_EDGES * 32;
        scatter_kernel<<<(int)((work + 255) / 256), 256, 0, stream>>>(x, emb, ei, ew, out);
        mfma_gemm<<<(N_NODES + 127) / 128, 256, 0, stream>>>(x, out, Bh, Bl, b_l, b_r);
    }
}

// Round 10
// 106.443 us; speedup vs baseline: 1.3781x; 1.0023x over previous
//
#include <hip/hip_runtime.h>

#define N_NODES 50000
#define N_EDGES 600000
#define D 128
#define SCAN_BLOCKS ((N_NODES + 255) / 256)   // 196
#define PAD 8                                  // segment padding multiple
#define PACK_CAP 950272                        // >= 600000+7*50000+16, =928*1024
#define PFILL_BLOCKS (PACK_CAP / 1024)         // 928
#define SENTINEL 50000u                        // src = zero row, w = 0

typedef __attribute__((ext_vector_type(8))) short short8v;
typedef __attribute__((ext_vector_type(4))) float f32x4;

__device__ __forceinline__ unsigned short f2bf(float v) {
    unsigned u = __builtin_bit_cast(unsigned, v);
    u += 0x7FFFu + ((u >> 16) & 1u);          // round-to-nearest-even
    return (unsigned short)(u >> 16);
}
__device__ __forceinline__ float bf2f(unsigned short h) {
    unsigned u = ((unsigned)h) << 16;
    return __builtin_bit_cast(float, u);
}

// == prep: W hi/lo + x -> bf16 hi/lo + zero counts + sentinel prefill ========
#define XPREP_BLOCKS ((N_NODES * D / 8 + 255) / 256)   // 3125
__global__ __launch_bounds__(256) void prep_kernel(
    const float* __restrict__ Wl, const float* __restrict__ Wr,
    unsigned short* __restrict__ Bh, unsigned short* __restrict__ Bl,
    const float* __restrict__ x,
    unsigned short* __restrict__ xh, unsigned short* __restrict__ xl,
    int* __restrict__ counts, unsigned* __restrict__ packed)
{
    int bid = blockIdx.x;
    if (bid < 128) {
        int t = bid * 256 + threadIdx.x;          // covers 128*256 W elements
        int n = t >> 8;
        int k = t & 255;
        float w = (k < 128) ? Wl[n * 128 + k] : Wr[n * 128 + (k - 128)];
        unsigned short h = f2bf(w);
        Bh[t] = h;
        Bl[t] = f2bf(w - bf2f(h));
    } else if (bid < 128 + XPREP_BLOCKS) {
        int t = (bid - 128) * 256 + threadIdx.x;  // 8 floats per thread
        if (t < N_NODES * D / 8) {
            const float4* p = (const float4*)(x + (size_t)t * 8);
            float4 a = p[0], b = p[1];
            float v[8] = {a.x, a.y, a.z, a.w, b.x, b.y, b.z, b.w};
            short8v oh, ol;
#pragma unroll
            for (int q = 0; q < 8; q++) {
                unsigned short h = f2bf(v[q]);
                oh[q] = (short)h;
                ol[q] = (short)f2bf(v[q] - bf2f(h));
            }
            *(short8v*)(xh + (size_t)t * 8) = oh;
            *(short8v*)(xl + (size_t)t * 8) = ol;
        }
    } else if (bid < 128 + XPREP_BLOCKS + SCAN_BLOCKS) {
        int t = (bid - 128 - XPREP_BLOCKS) * 256 + threadIdx.x;
        if (t < N_NODES) counts[t] = 0;
    } else if (bid < 128 + XPREP_BLOCKS + SCAN_BLOCKS + PFILL_BLOCKS) {
        int t = (bid - 128 - XPREP_BLOCKS - SCAN_BLOCKS) * 1024 + threadIdx.x * 4;
        uint4 s = make_uint4(SENTINEL, SENTINEL, SENTINEL, SENTINEL);
        *(uint4*)(packed + t) = s;
    } else {
        // zero row of xh at index N_NODES (gather target for sentinels)
        if (threadIdx.x < 16) {
            short8v z = (short8v){0,0,0,0,0,0,0,0};
            *(short8v*)(xh + (size_t)N_NODES * D + threadIdx.x * 8) = z;
        }
    }
}

// ============================== CSR-build path ==============================

__global__ __launch_bounds__(256) void histrank_kernel(
    const int* __restrict__ ei, int* __restrict__ counts,
    int* __restrict__ rank)
{
    int e = blockIdx.x * blockDim.x + threadIdx.x;
    if (e >= N_EDGES) return;
    rank[e] = atomicAdd(&counts[ei[N_EDGES + e]], 1);
}

// scans operate on PADDED counts: cp = (c+PAD-1) & ~(PAD-1)
__global__ __launch_bounds__(256) void scan_phase1(
    const int* __restrict__ counts, int* __restrict__ blockSums)
{
    int i = blockIdx.x * 256 + threadIdx.x;
    int v = (i < N_NODES) ? ((counts[i] + PAD - 1) & ~(PAD - 1)) : 0;
#pragma unroll
    for (int off = 32; off > 0; off >>= 1) v += __shfl_down(v, off, 64);
    __shared__ int wsum[4];
    int lane = threadIdx.x & 63, wid = threadIdx.x >> 6;
    if (lane == 0) wsum[wid] = v;
    __syncthreads();
    if (threadIdx.x == 0)
        blockSums[blockIdx.x] = wsum[0] + wsum[1] + wsum[2] + wsum[3];
}

// merged phase2+3: every block scans the 196 block sums in-LDS, then does its
// per-element scan with the derived block offset.
__global__ __launch_bounds__(256) void scan_phase23(
    const int* __restrict__ counts,
    const int* __restrict__ blockSums,
    int* __restrict__ offs)
{
    __shared__ int sh[256];
    int t = threadIdx.x;
    int bs = (t < SCAN_BLOCKS) ? blockSums[t] : 0;
    sh[t] = bs;
    __syncthreads();
    for (int off = 1; off < 256; off <<= 1) {
        int u = (t >= off) ? sh[t - off] : 0;
        __syncthreads();
        sh[t] += u;
        __syncthreads();
    }
    int blockOff = (blockIdx.x > 0) ? sh[blockIdx.x - 1] : 0;
    if (blockIdx.x == 0 && t == 0) offs[N_NODES] = sh[SCAN_BLOCKS - 1];

    int i = blockIdx.x * 256 + t;
    int v = (i < N_NODES) ? ((counts[i] + PAD - 1) & ~(PAD - 1)) : 0;
    int lane = t & 63, wid = t >> 6;
    int s = v;
#pragma unroll
    for (int off = 1; off < 64; off <<= 1) {
        int u = __shfl_up(s, off, 64);
        if (lane >= off) s += u;
    }
    __shared__ int wsum[4];
    if (lane == 63) wsum[wid] = s;
    __syncthreads();
    int wadd = 0;
    for (int w = 0; w < wid; w++) wadd += wsum[w];
    if (i < N_NODES)
        offs[i] = blockOff + s + wadd - v;
}

// pos = offs[dst] + rank[e]; no atomic in the chain; sentinel slots untouched
__global__ __launch_bounds__(256) void pack_kernel(
    const int* __restrict__ ei,
    const int* __restrict__ ew,
    const int* __restrict__ offs,
    const int* __restrict__ rank,
    unsigned* __restrict__ packed)
{
    int e = blockIdx.x * blockDim.x + threadIdx.x;
    if (e >= N_EDGES) return;
    int dst = ei[N_EDGES + e];
    int r   = rank[e];
    int pos = offs[dst] + r;
    packed[pos] = (unsigned)ei[e] | ((unsigned)ew[e] << 16);
}

// 2 nodes per wave (half-wave each, 4 cols/lane, 8B bf16 gathers).
// Segments padded to x8 with sentinels -> no per-edge masks; exhausted
// half-waves redirect to a sentinel block (zero row). Emits prop as bf16
// hi/lo pair (consumed directly by the MFMA GEMM staging).
__global__ __launch_bounds__(256) void aggregate_kernel(
    const unsigned short* __restrict__ xh,
    const float* __restrict__ emb,
    const int* __restrict__ offs,
    const unsigned* __restrict__ packed,
    unsigned short* __restrict__ ph, unsigned short* __restrict__ pl)
{
    __shared__ float emb_s[10][D];
    for (int i = threadIdx.x; i < 10 * D; i += 256)
        emb_s[i >> 7][i & 127] = emb[i];
    __syncthreads();

    int node = blockIdx.x * 8 + (threadIdx.x >> 5);
    if (node >= N_NODES) return;
    int c = (threadIdx.x & 31) * 4;

    int beg = offs[node], end = offs[node + 1];
    float4 acc = make_float4(0.f, 0.f, 0.f, 0.f);

    for (int i = beg; __any(i < end); i += PAD) {
        int ib = (i < end) ? i : (PACK_CAP - PAD);   // one cndmask per batch
        uint4 a0 = *(const uint4*)(packed + ib);
        uint4 a1 = *(const uint4*)(packed + ib + 4);
        unsigned pk[8] = {a0.x, a0.y, a0.z, a0.w, a1.x, a1.y, a1.z, a1.w};
        uint2 xr[8];
#pragma unroll
        for (int q = 0; q < 8; q++)
            xr[q] = *(const uint2*)(xh + (size_t)(pk[q] & 0xFFFFu) * D + c);
#pragma unroll
        for (int q = 0; q < 8; q++) {
            float4 er = *(const float4*)&emb_s[pk[q] >> 16][c];
            acc.x += er.x * bf2f((unsigned short)(xr[q].x & 0xFFFFu));
            acc.y += er.y * bf2f((unsigned short)(xr[q].x >> 16));
            acc.z += er.z * bf2f((unsigned short)(xr[q].y & 0xFFFFu));
            acc.w += er.w * bf2f((unsigned short)(xr[q].y >> 16));
        }
    }
    // split to bf16 hi/lo and store (8B each)
    float v[4] = {acc.x, acc.y, acc.z, acc.w};
    unsigned short h[4], l[4];
#pragma unroll
    for (int q = 0; q < 4; q++) {
        h[q] = f2bf(v[q]);
        l[q] = f2bf(v[q] - bf2f(h[q]));
    }
    unsigned h01 = (unsigned)h[0] | ((unsigned)h[1] << 16);
    unsigned h23 = (unsigned)h[2] | ((unsigned)h[3] << 16);
    unsigned l01 = (unsigned)l[0] | ((unsigned)l[1] << 16);
    unsigned l23 = (unsigned)l[2] | ((unsigned)l[3] << 16);
    *(uint2*)(ph + (size_t)node * D + c) = make_uint2(h01, h23);
    *(uint2*)(pl + (size_t)node * D + c) = make_uint2(l01, l23);
}

// ================= MFMA GEMM (pre-split bf16 sources) =======================
// out = [x | prop] @ [Wl^T ; Wr^T] + (b_l + b_r),   K = 256, N = 128
// A hi/lo from xh/xl (k<128) and ph/pl (k>=128); staging is pure copies.
__global__ __launch_bounds__(256) void mfma_gemm(
    const unsigned short* __restrict__ xh, const unsigned short* __restrict__ xl,
    const unsigned short* __restrict__ ph, const unsigned short* __restrict__ pl,
    float*       __restrict__ out,
    const unsigned short* __restrict__ Bh,  // [128][256]
    const unsigned short* __restrict__ Bl,
    const float* __restrict__ bl_,
    const float* __restrict__ br_)
{
    __shared__ unsigned short Ah_s[128 * 40];
    __shared__ unsigned short Al_s[128 * 40];
    __shared__ unsigned short Bh_s[128 * 40];
    __shared__ unsigned short Bl_s[128 * 40];

    const int tid  = threadIdx.x;
    const int lane = tid & 63;
    const int wave = tid >> 6;
    const int row0 = blockIdx.x * 128;

    const int wr0 = (wave >> 1) * 64;
    const int wc0 = (wave & 1) * 64;
    const int lr  = lane & 15;
    const int lk8 = (lane >> 4) * 8;

    const int srow  = tid >> 1;
    const int skoff = (tid & 1) * 16;

    f32x4 acc[4][4];
#pragma unroll
    for (int i = 0; i < 4; i++)
#pragma unroll
        for (int j = 0; j < 4; j++)
            acc[i][j] = (f32x4){0.f, 0.f, 0.f, 0.f};

    for (int kc = 0; kc < 8; ++kc) {
        const int kbase = kc * 32;
        {
            const unsigned short* sH = (kbase < 128) ? xh : ph;
            const unsigned short* sL = (kbase < 128) ? xl : pl;
            const size_t off = (size_t)(row0 + srow) * D + (kbase & 127) + skoff;
            short8v h0, h1, l0, l1;
            if (row0 + srow < N_NODES) {
                h0 = *(const short8v*)(sH + off);
                h1 = *(const short8v*)(sH + off + 8);
                l0 = *(const short8v*)(sL + off);
                l1 = *(const short8v*)(sL + off + 8);
            } else {
                h0 = h1 = l0 = l1 = (short8v){0,0,0,0,0,0,0,0};
            }
            *(short8v*)(Ah_s + srow * 40 + skoff)     = h0;
            *(short8v*)(Ah_s + srow * 40 + skoff + 8) = h1;
            *(short8v*)(Al_s + srow * 40 + skoff)     = l0;
            *(short8v*)(Al_s + srow * 40 + skoff + 8) = l1;
        }
        {
            const size_t boff = (size_t)srow * 256 + kbase + skoff;
            short8v bh0 = *(const short8v*)(Bh + boff);
            short8v bh1 = *(const short8v*)(Bh + boff + 8);
            short8v bl0 = *(const short8v*)(Bl + boff);
            short8v bl1 = *(const short8v*)(Bl + boff + 8);
            *(short8v*)(Bh_s + srow * 40 + skoff)     = bh0;
            *(short8v*)(Bh_s + srow * 40 + skoff + 8) = bh1;
            *(short8v*)(Bl_s + srow * 40 + skoff)     = bl0;
            *(short8v*)(Bl_s + srow * 40 + skoff + 8) = bl1;
        }
        __syncthreads();
        short8v afh[4], afl[4];
#pragma unroll
        for (int rt = 0; rt < 4; rt++) {
            int ar = wr0 + rt * 16 + lr;
            afh[rt] = *(const short8v*)(Ah_s + ar * 40 + lk8);
            afl[rt] = *(const short8v*)(Al_s + ar * 40 + lk8);
        }
#pragma unroll
        for (int ct = 0; ct < 4; ct++) {
            int bc = wc0 + ct * 16 + lr;
            short8v bfh = *(const short8v*)(Bh_s + bc * 40 + lk8);
            short8v bfl = *(const short8v*)(Bl_s + bc * 40 + lk8);
#pragma unroll
            for (int rt = 0; rt < 4; rt++)
                acc[rt][ct] = __builtin_amdgcn_mfma_f32_16x16x32_bf16(afh[rt], bfh, acc[rt][ct], 0, 0, 0);
#pragma unroll
            for (int rt = 0; rt < 4; rt++)
                acc[rt][ct] = __builtin_amdgcn_mfma_f32_16x16x32_bf16(afl[rt], bfh, acc[rt][ct], 0, 0, 0);
#pragma unroll
            for (int rt = 0; rt < 4; rt++)
                acc[rt][ct] = __builtin_amdgcn_mfma_f32_16x16x32_bf16(afh[rt], bfl, acc[rt][ct], 0, 0, 0);
        }
        __syncthreads();
    }

    const int drow = (lane >> 4) * 4;
#pragma unroll
    for (int ct = 0; ct < 4; ct++) {
        int col = wc0 + ct * 16 + lr;
        float bias = bl_[col] + br_[col];
#pragma unroll
        for (int rt = 0; rt < 4; rt++) {
#pragma unroll
            for (int r = 0; r < 4; r++) {
                int grow = row0 + wr0 + rt * 16 + drow + r;
                if (grow < N_NODES)
                    out[(size_t)grow * D + col] = acc[rt][ct][r] + bias;
            }
        }
    }
}

// ===================== fallback path (atomic, f32) ==========================

__global__ void zero_kernel(float4* __restrict__ out, int n4) {
    int i = blockIdx.x * blockDim.x + threadIdx.x;
    int stride = gridDim.x * blockDim.x;
    for (; i < n4; i += stride) out[i] = make_float4(0.f, 0.f, 0.f, 0.f);
}

__global__ __launch_bounds__(256) void scatter_kernel(
    const float* __restrict__ x,
    const float* __restrict__ emb,
    const int*   __restrict__ ei,
    const int*   __restrict__ ew,
    float*       __restrict__ prop)
{
    int gid = blockIdx.x * blockDim.x + threadIdx.x;
    int e = gid >> 5;
    if (e >= N_EDGES) return;
    int d4 = (gid & 31) * 4;
    int src = ei[e];
    int dst = ei[N_EDGES + e];
    int w   = ew[e];
    float4 ev = *(const float4*)(emb + (size_t)w * D + d4);
    float4 xv = *(const float4*)(x + (size_t)src * D + d4);
    float* p = prop + (size_t)dst * D + d4;
    atomicAdd(p + 0, ev.x * xv.x);
    atomicAdd(p + 1, ev.y * xv.y);
    atomicAdd(p + 2, ev.z * xv.z);
    atomicAdd(p + 3, ev.w * xv.w);
}

// fallback gemm: in-kernel f32 -> hi/lo split (x from global, prop from out)
__global__ __launch_bounds__(256) void mfma_gemm_fb(
    const float* __restrict__ x,
    float*       __restrict__ out,
    const unsigned short* __restrict__ Bh,
    const unsigned short* __restrict__ Bl,
    const float* __restrict__ bl_,
    const float* __restrict__ br_)
{
    __shared__ unsigned short Ah_s[128 * 40];
    __shared__ unsigned short Al_s[128 * 40];
    __shared__ unsigned short Bh_s[128 * 40];
    __shared__ unsigned short Bl_s[128 * 40];

    const int tid  = threadIdx.x;
    const int lane = tid & 63;
    const int wave = tid >> 6;
    const int row0 = blockIdx.x * 128;
    const int wr0 = (wave >> 1) * 64;
    const int wc0 = (wave & 1) * 64;
    const int lr  = lane & 15;
    const int lk8 = (lane >> 4) * 8;
    const int srow  = tid >> 1;
    const int skoff = (tid & 1) * 16;

    f32x4 acc[4][4];
#pragma unroll
    for (int i = 0; i < 4; i++)
#pragma unroll
        for (int j = 0; j < 4; j++)
            acc[i][j] = (f32x4){0.f, 0.f, 0.f, 0.f};

    for (int kc = 0; kc < 8; ++kc) {
        const int kbase = kc * 32;
        {
            const float* Asrc = (kbase < 128) ? x : out;
            const int acol = (kbase & 127) + skoff;
            const int grow = row0 + srow;
            float v[16];
            if (grow < N_NODES) {
                const float4* p = (const float4*)(Asrc + (size_t)grow * D + acol);
#pragma unroll
                for (int q = 0; q < 4; q++) {
                    float4 f = p[q];
                    v[q*4+0] = f.x; v[q*4+1] = f.y; v[q*4+2] = f.z; v[q*4+3] = f.w;
                }
            } else {
#pragma unroll
                for (int q = 0; q < 16; q++) v[q] = 0.f;
            }
            short8v h0, h1, l0, l1;
#pragma unroll
            for (int q = 0; q < 8; q++) {
                unsigned short h = f2bf(v[q]);
                h0[q] = (short)h;
                l0[q] = (short)f2bf(v[q] - bf2f(h));
            }
#pragma unroll
            for (int q = 0; q < 8; q++) {
                unsigned short h = f2bf(v[q + 8]);
                h1[q] = (short)h;
                l1[q] = (short)f2bf(v[q + 8] - bf2f(h));
            }
            *(short8v*)(Ah_s + srow * 40 + skoff)     = h0;
            *(short8v*)(Ah_s + srow * 40 + skoff + 8) = h1;
            *(short8v*)(Al_s + srow * 40 + skoff)     = l0;
            *(short8v*)(Al_s + srow * 40 + skoff + 8) = l1;
        }
        {
            const size_t boff = (size_t)srow * 256 + kbase + skoff;
            *(short8v*)(Bh_s + srow * 40 + skoff)     = *(const short8v*)(Bh + boff);
            *(short8v*)(Bh_s + srow * 40 + skoff + 8) = *(const short8v*)(Bh + boff + 8);
            *(short8v*)(Bl_s + srow * 40 + skoff)     = *(const short8v*)(Bl + boff);
            *(short8v*)(Bl_s + srow * 40 + skoff + 8) = *(const short8v*)(Bl + boff + 8);
        }
        __syncthreads();
        short8v afh[4], afl[4];
#pragma unroll
        for (int rt = 0; rt < 4; rt++) {
            int ar = wr0 + rt * 16 + lr;
            afh[rt] = *(const short8v*)(Ah_s + ar * 40 + lk8);
            afl[rt] = *(const short8v*)(Al_s + ar * 40 + lk8);
        }
#pragma unroll
        for (int ct = 0; ct < 4; ct++) {
            int bc = wc0 + ct * 16 + lr;
            short8v bfh = *(const short8v*)(Bh_s + bc * 40 + lk8);
            short8v bfl = *(const short8v*)(Bl_s + bc * 40 + lk8);
#pragma unroll
            for (int rt = 0; rt < 4; rt++)
                acc[rt][ct] = __builtin_amdgcn_mfma_f32_16x16x32_bf16(afh[rt], bfh, acc[rt][ct], 0, 0, 0);
#pragma unroll
            for (int rt = 0; rt < 4; rt++)
                acc[rt][ct] = __builtin_amdgcn_mfma_f32_16x16x32_bf16(afl[rt], bfh, acc[rt][ct], 0, 0, 0);
#pragma unroll
            for (int rt = 0; rt < 4; rt++)
                acc[rt][ct] = __builtin_amdgcn_mfma_f32_16x16x32_bf16(afh[rt], bfl, acc[rt][ct], 0, 0, 0);
        }
        __syncthreads();
    }

    const int drow = (lane >> 4) * 4;
#pragma unroll
    for (int ct = 0; ct < 4; ct++) {
        int col = wc0 + ct * 16 + lr;
        float bias = bl_[col] + br_[col];
#pragma unroll
        for (int rt = 0; rt < 4; rt++) {
#pragma unroll
            for (int r = 0; r < 4; r++) {
                int grow = row0 + wr0 + rt * 16 + drow + r;
                if (grow < N_NODES)
                    out[(size_t)grow * D + col] = acc[rt][ct][r] + bias;
            }
        }
    }
}

// ============================================================================
extern "C" void kernel_launch(void* const* d_in, const int* in_sizes, int n_in,
                              void* d_out, int out_size, void* d_ws, size_t ws_size,
                              hipStream_t stream) {
    const float* x    = (const float*)d_in[0];
    const float* emb  = (const float*)d_in[1];
    const float* W_l  = (const float*)d_in[2];
    const float* b_l  = (const float*)d_in[3];
    const float* W_r  = (const float*)d_in[4];
    const float* b_r  = (const float*)d_in[5];
    const int*   ei   = (const int*)d_in[6];
    const int*   ew   = (const int*)d_in[7];

    float* out = (float*)d_out;

    char* wsp = (char*)d_ws;
    unsigned short* Bh  = (unsigned short*)wsp; wsp += 128 * 256 * sizeof(unsigned short);
    unsigned short* Bl  = (unsigned short*)wsp; wsp += 128 * 256 * sizeof(unsigned short);
    unsigned short* xh  = (unsigned short*)wsp; wsp += (size_t)(N_NODES + 1) * D * sizeof(unsigned short);
    unsigned short* xl  = (unsigned short*)wsp; wsp += (size_t)N_NODES * D * sizeof(unsigned short);
    unsigned short* ph  = (unsigned short*)wsp; wsp += (size_t)N_NODES * D * sizeof(unsigned short);
    unsigned short* pl  = (unsigned short*)wsp; wsp += (size_t)N_NODES * D * sizeof(unsigned short);
    int*      counts    = (int*)wsp;     wsp += N_NODES * sizeof(int);
    int*      offs      = (int*)wsp;     wsp += (N_NODES + 1) * sizeof(int);
    int*      rank      = (int*)wsp;     wsp += N_EDGES * sizeof(int);
    int*      blockSums = (int*)wsp;     wsp += SCAN_BLOCKS * sizeof(int);
    unsigned* packed    = (unsigned*)wsp; wsp += (size_t)PACK_CAP * sizeof(unsigned);
    size_t needed = (size_t)(wsp - (char*)d_ws);

    if (ws_size >= needed) {
        prep_kernel<<<128 + XPREP_BLOCKS + SCAN_BLOCKS + PFILL_BLOCKS + 1, 256, 0, stream>>>(
            W_l, W_r, Bh, Bl, x, xh, xl, counts, packed);
        histrank_kernel<<<(N_EDGES + 255) / 256, 256, 0, stream>>>(ei, counts, rank);
        scan_phase1<<<SCAN_BLOCKS, 256, 0, stream>>>(counts, blockSums);
        scan_phase23<<<SCAN_BLOCKS, 256, 0, stream>>>(counts, blockSums, offs);
        pack_kernel<<<(N_EDGES + 255) / 256, 256, 0, stream>>>(ei, ew, offs, rank, packed);
        aggregate_kernel<<<(N_NODES + 7) / 8, 256, 0, stream>>>(xh, emb, offs, packed, ph, pl);
        mfma_gemm<<<(N_NODES + 127) / 128, 256, 0, stream>>>(xh, xl, ph, pl, out, Bh, Bl, b_l, b_r);
    } else {
        prep_kernel<<<128, 256, 0, stream>>>(W_l, W_r, Bh, Bl, x, xh, xl, counts, packed);
        int n4 = N_NODES * D / 4;
        zero_kernel<<<(n4 + 255) / 256, 256, 0, stream>>>((float4*)out, n4);
        long long work = (long long)N_EDGES * 32;
        scatter_kernel<<<(int)((work + 255) / 256), 256, 0, stream>>>(x, emb, ei, ew, out);
        mfma_gemm_fb<<<(N_NODES + 127) / 128, 256, 0, stream>>>(x, out, Bh, Bl, b_l, b_r);
    }
}